// Round 14
// baseline (182.617 us; speedup 1.0000x reference)
//
#include <hip/hip_runtime.h>
#include <hip/hip_bf16.h>

#define DDIM 2048
#define TTIMES 256
#define NT 64                 // K-steps of 32
#define THREADS 512

typedef __attribute__((ext_vector_type(8))) short short8;
typedef __attribute__((ext_vector_type(4))) float f32x4;

using gvoid = const __attribute__((address_space(1))) void;
using svoid = __attribute__((address_space(3))) void;

__device__ __forceinline__ void gld16(const void* g, void* l) {
    __builtin_amdgcn_global_load_lds((gvoid*)g, (svoid*)l, 16, 0, 0);
}

__device__ __forceinline__ ushort f2bf(float f) {
    union { float f; unsigned int u; } v; v.f = f;
    unsigned int u = v.u;
    unsigned int r = (u + 0x7FFFu + ((u >> 16) & 1u)) >> 16;   // RNE
    return (ushort)r;
}
__device__ __forceinline__ float bf2f(ushort u) {
    union { unsigned int u; float f; } v; v.u = ((unsigned int)u) << 16;
    return v.f;
}
__device__ __forceinline__ short cvt1(float f) {
    union { __hip_bfloat16 h; ushort u; } cv;
    cv.h = __float2bfloat16(f);          // hardware RNE cvt
    return (short)cv.u;
}

// ---------------- normalize org rows -> bf16 o in workspace ----------------
__global__ void norm_rows(const float* __restrict__ org, ushort* __restrict__ obf) {
    const int a   = blockIdx.x;     // time row
    const int tid = threadIdx.x;    // 256 threads
    const float* row = org + (size_t)a * DDIM;
    float4 v0 = ((const float4*)row)[tid * 2];
    float4 v1 = ((const float4*)row)[tid * 2 + 1];
    float s = v0.x*v0.x + v0.y*v0.y + v0.z*v0.z + v0.w*v0.w
            + v1.x*v1.x + v1.y*v1.y + v1.z*v1.z + v1.w*v1.w;
    #pragma unroll
    for (int off = 1; off < 64; off <<= 1) s += __shfl_xor(s, off);
    __shared__ float wsum[4];
    const int lane = tid & 63, w = tid >> 6;
    if (lane == 0) wsum[w] = s;
    __syncthreads();
    const float tot = wsum[0] + wsum[1] + wsum[2] + wsum[3];
    const float scale = 1.0f / fmaxf(sqrtf(tot), 1e-12f);
    union { ushort u[8]; uint4 v; } pk;
    pk.u[0] = f2bf(v0.x * scale); pk.u[1] = f2bf(v0.y * scale);
    pk.u[2] = f2bf(v0.z * scale); pk.u[3] = f2bf(v0.w * scale);
    pk.u[4] = f2bf(v1.x * scale); pk.u[5] = f2bf(v1.y * scale);
    pk.u[6] = f2bf(v1.z * scale); pk.u[7] = f2bf(v1.w * scale);
    ((uint4*)(obf + (size_t)a * DDIM))[tid] = pk.v;
}

// ---- R11 skeleton, B read global->VGPR (L1/L2-hot), A-only LDS ----
// A: 3-deep gld16 DMA (2-step HBM lead), 48 KB LDS, 1 barrier/step, stagger.
// B: obf L2-resident; fragments loaded in-compute, issued AFTER barrier and
// BEFORE STAGE_A(t+2) so the compiler's B-wait (vmcnt<=2, in-order retire)
// retires A(t+1) (due next step anyway) and keeps A(t+2) flying.
// LDS traffic/step: 128 -> 80 KB at constant 16 waves/CU.
__global__ __launch_bounds__(THREADS, 4) void gemm_trace(
    const float* __restrict__ x, const ushort* __restrict__ obf,
    float* __restrict__ part)
{
    __shared__ __align__(16) char Ab[3][16384];   // fp32 A tiles: 128 rows x 32 k

    const int tid  = threadIdx.x;
    const int lane = tid & 63;
    const int wid  = tid >> 6;      // 0..7
    const int wm   = wid >> 2;      // 0..1 (row half)
    const int wn   = wid & 3;       // 0..3 (time quarter)
    const int rb   = blockIdx.x;    // 0..15 (row block of 128)
    const int d    = blockIdx.y;    // 0..31 (batch)
    const int t0   = (d * 16 + rb) & (NT - 1);   // K stagger phase
#define W(n) ((t0 + (n)) & (NT - 1))

    const char* ab = (const char*)(x + (size_t)d * DDIM * DDIM + (size_t)rb * 128 * DDIM);

    // A staging: 1024 chunks (128 rows x 8); 2 per thread; src pre-swizzled
    const int ar0 = tid >> 3,         aq0 = ((tid & 7) ^ (ar0 & 7)) * 16;
    const int ar1 = (tid + 512) >> 3, aq1 = (((tid + 512) & 7) ^ (ar1 & 7)) * 16;
    const char* as0 = ab + (size_t)ar0 * (DDIM * 4) + aq0;
    const char* as1 = ab + (size_t)ar1 * (DDIM * 4) + aq1;

#define STAGE_A(t, buf) do {                                  \
    gld16(as0 + (t) * 128, &Ab[buf][tid * 16]);               \
    gld16(as1 + (t) * 128, &Ab[buf][(tid + 512) * 16]);       \
} while (0)

    const int lr = lane & 15;       // row-in-16 (A) / time-in-16 (B)
    const int lq = lane >> 4;       // k-quarter

    int aoff0[4], aoff1[4];
    #pragma unroll
    for (int mi = 0; mi < 4; ++mi) {
        const int r = wm * 64 + mi * 16 + lr;
        aoff0[mi] = r * 128 + ((2 * lq)     ^ (r & 7)) * 16;
        aoff1[mi] = r * 128 + ((2 * lq + 1) ^ (r & 7)) * 16;
    }
    // B fragment global base pointers (per ni); step offset = W(t)*32 ushorts
    const ushort* btp[4];
    #pragma unroll
    for (int ni = 0; ni < 4; ++ni)
        btp[ni] = obf + (size_t)(wn * 64 + ni * 16 + lr) * DDIM + lq * 8;

    f32x4 acc[4][4];
    #pragma unroll
    for (int mi = 0; mi < 4; ++mi)
        #pragma unroll
        for (int ni = 0; ni < 4; ++ni)
            acc[mi][ni] = (f32x4){0.f, 0.f, 0.f, 0.f};

#define COMPUTE(abuf, T) do {                                               \
    short8 bfr[4];                                                          \
    _Pragma("unroll")                                                       \
    for (int ni = 0; ni < 4; ++ni)                                          \
        bfr[ni] = *(const short8*)(btp[ni] + (size_t)(T) * 32);             \
    short8 af[4];                                                           \
    _Pragma("unroll")                                                       \
    for (int mi = 0; mi < 4; ++mi) {                                        \
        const float4 lo = *(const float4*)&Ab[abuf][aoff0[mi]];             \
        const float4 hi = *(const float4*)&Ab[abuf][aoff1[mi]];             \
        short8 a8;                                                          \
        a8[0] = cvt1(lo.x); a8[1] = cvt1(lo.y);                             \
        a8[2] = cvt1(lo.z); a8[3] = cvt1(lo.w);                             \
        a8[4] = cvt1(hi.x); a8[5] = cvt1(hi.y);                             \
        a8[6] = cvt1(hi.z); a8[7] = cvt1(hi.w);                             \
        af[mi] = a8;                                                        \
    }                                                                       \
    _Pragma("unroll")                                                       \
    for (int mi = 0; mi < 4; ++mi)                                          \
        _Pragma("unroll")                                                   \
        for (int ni = 0; ni < 4; ++ni)                                      \
            acc[mi][ni] = __builtin_amdgcn_mfma_f32_16x16x32_bf16(          \
                af[mi], bfr[ni], acc[mi][ni], 0, 0, 0);                     \
} while (0)

#define VMW(n) do {                                                         \
    asm volatile("s_waitcnt vmcnt(" #n ")" ::: "memory");                   \
    __builtin_amdgcn_sched_barrier(0); } while (0)
#define SBAR do {                                                           \
    __builtin_amdgcn_sched_barrier(0);                                      \
    asm volatile("s_waitcnt lgkmcnt(0)" ::: "memory");                      \
    __builtin_amdgcn_s_barrier();                                           \
    __builtin_amdgcn_sched_barrier(0); } while (0)

    // ---- prologue: A(0)->0, A(1)->1 ----
    STAGE_A(W(0), 0);
    STAGE_A(W(1), 1);

    int abf = 0;                   // t % 3 at loop top
    #pragma unroll 1
    for (int t = 0; t < NT - 1; ++t) {
        VMW(2);                    // retire A(t) (at most); keep A(t+1) flying
        SBAR;                      // compute(t-1) reads proven done
        if (t + 2 < NT) {
            int ab2 = abf + 2; if (ab2 >= 3) ab2 -= 3;
            STAGE_A(W(t + 2), ab2);
        }
        COMPUTE(abf, W(t));        // B loads issue first inside; queue keeps A(t+2)
        ++abf; if (abf == 3) abf = 0;
    }
    // ---- last step t = NT-1 ----
    VMW(0);
    SBAR;
    COMPUTE(abf, W(NT - 1));
    __syncthreads();

#undef W
#undef STAGE_A
#undef COMPUTE
#undef VMW
#undef SBAR

    // ---- fused trace epilogue ----
    // acc[mi][ni][j]: row = rb*128 + wm*64 + mi*16 + lq*4 + j, time = wn*64 + ni*16 + lr
    float* plds = (float*)&Ab[0][0];   // 2 x 256 floats (LDS free now)

    #pragma unroll
    for (int ni = 0; ni < 4; ++ni) {
        const int a_idx = wn * 64 + ni * 16 + lr;
        float ps = 0.f;
        #pragma unroll
        for (int mi = 0; mi < 4; ++mi) {
            const int bg = rb * 128 + wm * 64 + mi * 16 + lq * 4;
            const ushort4 w = *(const ushort4*)(obf + (size_t)a_idx * DDIM + bg);
            ps += bf2f(w.x) * acc[mi][ni][0];
            ps += bf2f(w.y) * acc[mi][ni][1];
            ps += bf2f(w.z) * acc[mi][ni][2];
            ps += bf2f(w.w) * acc[mi][ni][3];
        }
        ps += __shfl_xor(ps, 16);
        ps += __shfl_xor(ps, 32);
        if (lane < 16) plds[wm * 256 + a_idx] = ps;
    }
    __syncthreads();
    if (tid < 256)
        part[((size_t)d * 16 + rb) * TTIMES + tid] = plds[tid] + plds[256 + tid];
}

// ---------------- final reduce over row-blocks ----------------
__global__ void reduce_part(const float* __restrict__ part, float* __restrict__ out) {
    const int d = blockIdx.x;    // 32
    const int a = threadIdx.x;   // 256
    float s = 0.f;
    #pragma unroll
    for (int rb = 0; rb < 16; ++rb)
        s += part[((size_t)d * 16 + rb) * TTIMES + a];
    out[(size_t)d * TTIMES + a] = s;
}

extern "C" void kernel_launch(void* const* d_in, const int* in_sizes, int n_in,
                              void* d_out, int out_size, void* d_ws, size_t ws_size,
                              hipStream_t stream) {
    const float* x   = (const float*)d_in[0];   // (32, 2048, 2048) fp32
    const float* org = (const float*)d_in[1];   // (256, 2048) fp32
    float* out = (float*)d_out;                 // (32, 256) fp32

    ushort* obf = (ushort*)d_ws;                          // 1 MiB bf16 normalized o
    float*  prt = (float*)((char*)d_ws + (1 << 20));      // 512 KiB partials (32x16x256)

    norm_rows<<<dim3(TTIMES), dim3(256), 0, stream>>>(org, obf);
    gemm_trace<<<dim3(16, 32), dim3(THREADS), 0, stream>>>(x, obf, prt);
    reduce_part<<<dim3(32), dim3(256), 0, stream>>>(prt, out);
}

// Round 15
// 138.551 us; speedup vs baseline: 1.3180x; 1.3180x over previous
//
#include <hip/hip_runtime.h>
#include <hip/hip_bf16.h>

#define DDIM 2048
#define TTIMES 256
#define NTA 32                // A-steps of 64 k (2 substeps of 32 each)
#define THREADS 512

typedef __attribute__((ext_vector_type(8))) short short8;
typedef __attribute__((ext_vector_type(4))) float f32x4;

using gvoid = const __attribute__((address_space(1))) void;
using svoid = __attribute__((address_space(3))) void;

__device__ __forceinline__ void gld16(const void* g, void* l) {
    __builtin_amdgcn_global_load_lds((gvoid*)g, (svoid*)l, 16, 0, 0);
}

__device__ __forceinline__ ushort f2bf(float f) {
    union { float f; unsigned int u; } v; v.f = f;
    unsigned int u = v.u;
    unsigned int r = (u + 0x7FFFu + ((u >> 16) & 1u)) >> 16;   // RNE
    return (ushort)r;
}
__device__ __forceinline__ float bf2f(ushort u) {
    union { unsigned int u; float f; } v; v.u = ((unsigned int)u) << 16;
    return v.f;
}
__device__ __forceinline__ ushort cvt1(float f) {
    union { __hip_bfloat16 h; ushort u; } cv;
    cv.h = __float2bfloat16(f);          // hardware RNE cvt
    return cv.u;
}

// ---------------- normalize org rows -> bf16 o in workspace ----------------
__global__ void norm_rows(const float* __restrict__ org, ushort* __restrict__ obf) {
    const int a   = blockIdx.x;
    const int tid = threadIdx.x;    // 256 threads
    const float* row = org + (size_t)a * DDIM;
    float4 v0 = ((const float4*)row)[tid * 2];
    float4 v1 = ((const float4*)row)[tid * 2 + 1];
    float s = v0.x*v0.x + v0.y*v0.y + v0.z*v0.z + v0.w*v0.w
            + v1.x*v1.x + v1.y*v1.y + v1.z*v1.z + v1.w*v1.w;
    #pragma unroll
    for (int off = 1; off < 64; off <<= 1) s += __shfl_xor(s, off);
    __shared__ float wsum[4];
    const int lane = tid & 63, w = tid >> 6;
    if (lane == 0) wsum[w] = s;
    __syncthreads();
    const float tot = wsum[0] + wsum[1] + wsum[2] + wsum[3];
    const float scale = 1.0f / fmaxf(sqrtf(tot), 1e-12f);
    union { ushort u[8]; uint4 v; } pk;
    pk.u[0] = f2bf(v0.x * scale); pk.u[1] = f2bf(v0.y * scale);
    pk.u[2] = f2bf(v0.z * scale); pk.u[3] = f2bf(v0.w * scale);
    pk.u[4] = f2bf(v1.x * scale); pk.u[5] = f2bf(v1.y * scale);
    pk.u[6] = f2bf(v1.z * scale); pk.u[7] = f2bf(v1.w * scale);
    ((uint4*)(obf + (size_t)a * DDIM))[tid] = pk.v;
}

// ---- bf16-A in LDS (BK=64, 256-B runs), barrier-pinned reg staging ----
// 8 waves (2 wm x 4 wn), tile 128x256. A: 4xfloat4/thread loaded at odd
// substep of T, cvt+swizzled ds_write at odd substep of T+1 (2-substep
// flight pinned by asm-memory barriers -> compiler can't sink). B: gld16
// BK=32 2-deep (R11-identical). LDS 2x16(A bf16) + 2x16(B) = 64 KB ->
// 2 blocks/CU. vmcnt: even substep (4) [retire B, keep A], odd (0).
__global__ __launch_bounds__(THREADS, 4) void gemm_trace(
    const float* __restrict__ x, const ushort* __restrict__ obf,
    float* __restrict__ part)
{
    __shared__ __align__(16) ushort Ab[2][8192];    // bf16 A: 128 rows x 64 k
    __shared__ __align__(16) char   Bb[2][16384];   // bf16 B: 256 rows x 32 k

    const int tid  = threadIdx.x;
    const int lane = tid & 63;
    const int wid  = tid >> 6;      // 0..7
    const int wm   = wid >> 2;      // 0..1 (row half)
    const int wn   = wid & 3;       // 0..3 (time quarter)
    const int rb   = blockIdx.x;    // 0..15 (row block of 128)
    const int d    = blockIdx.y;    // 0..31 (batch)
    const int T0   = (d * 16 + rb) & (NTA - 1);   // A-step stagger phase
#define W(n) ((T0 + (n)) & (NTA - 1))

    // ---- A staging: thread owns row tid>>2, 64 B chunk tid&3 ----
    const int arow = tid >> 2, ac = tid & 3;
    const float* asrc = x + (size_t)d * DDIM * DDIM
                          + (size_t)(rb * 128 + arow) * DDIM + ac * 16;
    const int awoff0 = arow * 64 + (((ac * 2)     ^ (arow & 7)) * 8);  // ushorts
    const int awoff1 = arow * 64 + (((ac * 2 + 1) ^ (arow & 7)) * 8);

    // ---- B staging (R11-identical): linear DMA dest, pre-swizzled src ----
    const char* bs0 = (const char*)obf + (size_t)(tid >> 2) * (DDIM * 2)
                    + ((tid & 3) ^ ((tid >> 2) & 3)) * 16;
    const char* bs1 = bs0 + (size_t)128 * (DDIM * 2);

    // ---- fragment indexing ----
    const int lr = lane & 15, lq = lane >> 4;
    int abase[4], arx[4], boff[4];
    #pragma unroll
    for (int mi = 0; mi < 4; ++mi) {
        const int r = wm * 64 + mi * 16 + lr;
        abase[mi] = r * 64;        // ushort units (row stride 64 ushorts)
        arx[mi]   = r & 7;
    }
    #pragma unroll
    for (int ni = 0; ni < 4; ++ni) {
        const int rt = wn * 64 + ni * 16 + lr;
        boff[ni] = rt * 64 + (lq ^ (rt & 3)) * 16;   // bytes
    }

    f32x4 acc[4][4];
    #pragma unroll
    for (int mi = 0; mi < 4; ++mi)
        #pragma unroll
        for (int ni = 0; ni < 4; ++ni)
            acc[mi][ni] = (f32x4){0.f, 0.f, 0.f, 0.f};

    float4 a0, a1, a2, a3;          // A staging regs (one T in flight)

#define ALOAD(T) do {                                                       \
    const float* p_ = asrc + (size_t)(W(T)) * 64;                           \
    a0 = *(const float4*)p_;       a1 = *(const float4*)(p_ + 4);           \
    a2 = *(const float4*)(p_ + 8); a3 = *(const float4*)(p_ + 12);          \
} while (0)

#define WRITE_A(buf) do {                                                   \
    union { ushort u[8]; uint4 v; } pk_;                                    \
    pk_.u[0] = cvt1(a0.x); pk_.u[1] = cvt1(a0.y);                           \
    pk_.u[2] = cvt1(a0.z); pk_.u[3] = cvt1(a0.w);                           \
    pk_.u[4] = cvt1(a1.x); pk_.u[5] = cvt1(a1.y);                           \
    pk_.u[6] = cvt1(a1.z); pk_.u[7] = cvt1(a1.w);                           \
    *(uint4*)&Ab[buf][awoff0] = pk_.v;                                      \
    pk_.u[0] = cvt1(a2.x); pk_.u[1] = cvt1(a2.y);                           \
    pk_.u[2] = cvt1(a2.z); pk_.u[3] = cvt1(a2.w);                           \
    pk_.u[4] = cvt1(a3.x); pk_.u[5] = cvt1(a3.y);                           \
    pk_.u[6] = cvt1(a3.z); pk_.u[7] = cvt1(a3.w);                           \
    *(uint4*)&Ab[buf][awoff1] = pk_.v;                                      \
} while (0)

#define STAGE_B(T, ksub, buf) do {                                          \
    const size_t off_ = (size_t)(W(T)) * 128 + (ksub) * 64;                 \
    gld16(bs0 + off_, &Bb[buf][tid * 16]);                                  \
    gld16(bs1 + off_, &Bb[buf][8192 + tid * 16]);                           \
} while (0)

#define COMPUTE(abuf, ksub, bbuf) do {                                      \
    short8 af[4], bfr[4];                                                   \
    _Pragma("unroll")                                                       \
    for (int mi = 0; mi < 4; ++mi)                                          \
        af[mi] = *(const short8*)                                           \
            &Ab[abuf][abase[mi] + ((((ksub) * 4 + lq) ^ arx[mi]) * 8)];     \
    _Pragma("unroll")                                                       \
    for (int ni = 0; ni < 4; ++ni)                                          \
        bfr[ni] = *(const short8*)&Bb[bbuf][boff[ni]];                      \
    _Pragma("unroll")                                                       \
    for (int mi = 0; mi < 4; ++mi)                                          \
        _Pragma("unroll")                                                   \
        for (int ni = 0; ni < 4; ++ni)                                      \
            acc[mi][ni] = __builtin_amdgcn_mfma_f32_16x16x32_bf16(          \
                af[mi], bfr[ni], acc[mi][ni], 0, 0, 0);                     \
} while (0)

#define VMW(n) do {                                                         \
    asm volatile("s_waitcnt vmcnt(" #n ")" ::: "memory");                   \
    __builtin_amdgcn_sched_barrier(0); } while (0)
#define SBAR do {                                                           \
    __builtin_amdgcn_sched_barrier(0);                                      \
    asm volatile("s_waitcnt lgkmcnt(0)" ::: "memory");                      \
    __builtin_amdgcn_s_barrier();                                           \
    __builtin_amdgcn_sched_barrier(0); } while (0)

    // ---- prologue: A(0)->regs->LDS0; B(0,0); A(1)->regs ----
    ALOAD(0);
    WRITE_A(0);                    // compiler waits A(0) arrival here
    STAGE_B(0, 0, 0);              // queue: B0^2
    ALOAD(1);                      // queue: B0^2, A1^4
    // (substep 0's VMW(4)+SBAR covers B0 + the ds_writes)

    #pragma unroll 1
    for (int T = 0; T < NTA - 1; ++T) {
        const int ab_ = T & 1;
        // even substep: queue [B(T,0)^2, A(T+1)^4]
        VMW(4);                    // retire B(T,0); keep A(T+1) flying
        SBAR;
        STAGE_B(T, 1, 1);
        COMPUTE(ab_, 0, 0);
        // odd substep: queue [A(T+1)^4, B(T,1)^2]
        VMW(0);                    // all due now (A written below, B consumed)
        SBAR;
        STAGE_B(T + 1, 0, 0);
        WRITE_A(ab_ ^ 1);          // A(T+1) -> other buffer
        if (T + 2 < NTA) ALOAD(T + 2);
        COMPUTE(ab_, 1, 1);
    }
    // ---- T = NTA-1 (A already in LDS buf 1) ----
    VMW(0);
    SBAR;
    STAGE_B(NTA - 1, 1, 1);
    COMPUTE(1, 0, 0);
    VMW(0);
    SBAR;
    COMPUTE(1, 1, 1);
    __syncthreads();

#undef W
#undef ALOAD
#undef WRITE_A
#undef STAGE_B
#undef COMPUTE
#undef VMW
#undef SBAR

    // ---- fused trace epilogue ----
    // acc[mi][ni][j]: row = rb*128 + wm*64 + mi*16 + lq*4 + j,
    //                 time = wn*64 + ni*16 + lr
    float* plds = (float*)&Ab[0][0];   // 2 x 256 floats (LDS free now)

    #pragma unroll
    for (int ni = 0; ni < 4; ++ni) {
        const int a_idx = wn * 64 + ni * 16 + lr;
        float ps = 0.f;
        #pragma unroll
        for (int mi = 0; mi < 4; ++mi) {
            const int bg = rb * 128 + wm * 64 + mi * 16 + lq * 4;
            const ushort4 w = *(const ushort4*)(obf + (size_t)a_idx * DDIM + bg);
            ps += bf2f(w.x) * acc[mi][ni][0];
            ps += bf2f(w.y) * acc[mi][ni][1];
            ps += bf2f(w.z) * acc[mi][ni][2];
            ps += bf2f(w.w) * acc[mi][ni][3];
        }
        ps += __shfl_xor(ps, 16);
        ps += __shfl_xor(ps, 32);
        if (lane < 16) plds[wm * 256 + a_idx] = ps;
    }
    __syncthreads();
    if (tid < 256)
        part[((size_t)d * 16 + rb) * TTIMES + tid] = plds[tid] + plds[256 + tid];
}

// ---------------- final reduce over row-blocks ----------------
__global__ void reduce_part(const float* __restrict__ part, float* __restrict__ out) {
    const int d = blockIdx.x;    // 32
    const int a = threadIdx.x;   // 256
    float s = 0.f;
    #pragma unroll
    for (int rb = 0; rb < 16; ++rb)
        s += part[((size_t)d * 16 + rb) * TTIMES + a];
    out[(size_t)d * TTIMES + a] = s;
}

extern "C" void kernel_launch(void* const* d_in, const int* in_sizes, int n_in,
                              void* d_out, int out_size, void* d_ws, size_t ws_size,
                              hipStream_t stream) {
    const float* x   = (const float*)d_in[0];   // (32, 2048, 2048) fp32
    const float* org = (const float*)d_in[1];   // (256, 2048) fp32
    float* out = (float*)d_out;                 // (32, 256) fp32

    ushort* obf = (ushort*)d_ws;                          // 1 MiB bf16 normalized o
    float*  prt = (float*)((char*)d_ws + (1 << 20));      // 512 KiB partials (32x16x256)

    norm_rows<<<dim3(TTIMES), dim3(256), 0, stream>>>(org, obf);
    gemm_trace<<<dim3(16, 32), dim3(THREADS), 0, stream>>>(x, obf, prt);
    reduce_part<<<dim3(32), dim3(256), 0, stream>>>(prt, out);
}

// Round 16
// 129.661 us; speedup vs baseline: 1.4084x; 1.0686x over previous
//
#include <hip/hip_runtime.h>
#include <hip/hip_bf16.h>

#define DDIM 2048
#define TTIMES 256
#define NT 64                 // K-steps of 32
#define THREADS 512

typedef __attribute__((ext_vector_type(8))) short short8;
typedef __attribute__((ext_vector_type(4))) float f32x4;

using gvoid = const __attribute__((address_space(1))) void;
using svoid = __attribute__((address_space(3))) void;

__device__ __forceinline__ void gld16(const void* g, void* l) {
    __builtin_amdgcn_global_load_lds((gvoid*)g, (svoid*)l, 16, 0, 0);
}

__device__ __forceinline__ ushort f2bf(float f) {
    union { float f; unsigned int u; } v; v.f = f;
    unsigned int u = v.u;
    unsigned int r = (u + 0x7FFFu + ((u >> 16) & 1u)) >> 16;   // RNE
    return (ushort)r;
}
__device__ __forceinline__ float bf2f(ushort u) {
    union { unsigned int u; float f; } v; v.u = ((unsigned int)u) << 16;
    return v.f;
}
__device__ __forceinline__ short cvt1(float f) {
    union { __hip_bfloat16 h; ushort u; } cv;
    cv.h = __float2bfloat16(f);          // hardware RNE cvt
    return (short)cv.u;
}

// ---------------- normalize org rows -> bf16 o in workspace ----------------
__global__ void norm_rows(const float* __restrict__ org, ushort* __restrict__ obf) {
    const int a   = blockIdx.x;     // time row
    const int tid = threadIdx.x;    // 256 threads
    const float* row = org + (size_t)a * DDIM;
    float4 v0 = ((const float4*)row)[tid * 2];
    float4 v1 = ((const float4*)row)[tid * 2 + 1];
    float s = v0.x*v0.x + v0.y*v0.y + v0.z*v0.z + v0.w*v0.w
            + v1.x*v1.x + v1.y*v1.y + v1.z*v1.z + v1.w*v1.w;
    #pragma unroll
    for (int off = 1; off < 64; off <<= 1) s += __shfl_xor(s, off);
    __shared__ float wsum[4];
    const int lane = tid & 63, w = tid >> 6;
    if (lane == 0) wsum[w] = s;
    __syncthreads();
    const float tot = wsum[0] + wsum[1] + wsum[2] + wsum[3];
    const float scale = 1.0f / fmaxf(sqrtf(tot), 1e-12f);
    union { ushort u[8]; uint4 v; } pk;
    pk.u[0] = f2bf(v0.x * scale); pk.u[1] = f2bf(v0.y * scale);
    pk.u[2] = f2bf(v0.z * scale); pk.u[3] = f2bf(v0.w * scale);
    pk.u[4] = f2bf(v1.x * scale); pk.u[5] = f2bf(v1.y * scale);
    pk.u[6] = f2bf(v1.z * scale); pk.u[7] = f2bf(v1.w * scale);
    ((uint4*)(obf + (size_t)a * DDIM))[tid] = pk.v;
}

// ---- R11 + scrambled K-phase stagger (t0 = bid*37 mod 64) ----
// Consecutive dispatch IDs (-> co-resident on a CU / same XCD) now get
// K-phases 37 apart instead of adjacent, so each CU's in-flight loads span
// well-separated DRAM column bands (channel spread at the CU-queue level,
// not just globally). Everything else identical to the 129.9 us R11.
__global__ __launch_bounds__(THREADS, 4) void gemm_trace(
    const float* __restrict__ x, const ushort* __restrict__ obf,
    float* __restrict__ part)
{
    __shared__ __align__(16) char Ab[3][16384];   // fp32 A tiles: 128 rows x 32 k
    __shared__ __align__(16) char Bb[2][16384];   // bf16 B tiles: 256 rows x 32 k

    const int tid  = threadIdx.x;
    const int lane = tid & 63;
    const int wid  = tid >> 6;      // 0..7
    const int wm   = wid >> 2;      // 0..1 (row half)
    const int wn   = wid & 3;       // 0..3 (time quarter)
    const int rb   = blockIdx.x;    // 0..15 (row block of 128)
    const int d    = blockIdx.y;    // 0..31 (batch)
    const int t0   = ((d * 16 + rb) * 37) & (NT - 1);   // scrambled K phase
#define W(n) ((t0 + (n)) & (NT - 1))

    const char* ab = (const char*)(x + (size_t)d * DDIM * DDIM + (size_t)rb * 128 * DDIM);
    const char* bb = (const char*)obf;

    // staging: A 1024 chunks (128 rows x 8), B 1024 chunks (256 rows x 4); 2 each/thread
    const int ar0 = tid >> 3,         aq0 = ((tid & 7) ^ (ar0 & 7)) * 16;
    const int ar1 = (tid + 512) >> 3, aq1 = (((tid + 512) & 7) ^ (ar1 & 7)) * 16;
    const int br0 = tid >> 2,         bq0 = ((tid & 3) ^ (br0 & 3)) * 16;
    const int br1 = (tid + 512) >> 2, bq1 = (((tid + 512) & 3) ^ (br1 & 3)) * 16;

    const char* as0 = ab + (size_t)ar0 * (DDIM * 4) + aq0;
    const char* as1 = ab + (size_t)ar1 * (DDIM * 4) + aq1;
    const char* bs0 = bb + (size_t)br0 * (DDIM * 2) + bq0;
    const char* bs1 = bb + (size_t)br1 * (DDIM * 2) + bq1;

#define STAGE_A(t, buf) do {                                  \
    gld16(as0 + (t) * 128, &Ab[buf][tid * 16]);               \
    gld16(as1 + (t) * 128, &Ab[buf][(tid + 512) * 16]);       \
} while (0)
#define STAGE_B(t, buf) do {                                  \
    gld16(bs0 + (t) * 64,  &Bb[buf][tid * 16]);               \
    gld16(bs1 + (t) * 64,  &Bb[buf][(tid + 512) * 16]);       \
} while (0)

    const int lr = lane & 15;       // row-in-16 (A) / time-in-16 (B)
    const int lq = lane >> 4;       // k-quarter

    int aoff0[4], aoff1[4], boff[4];
    #pragma unroll
    for (int mi = 0; mi < 4; ++mi) {
        const int r = wm * 64 + mi * 16 + lr;
        aoff0[mi] = r * 128 + ((2 * lq)     ^ (r & 7)) * 16;
        aoff1[mi] = r * 128 + ((2 * lq + 1) ^ (r & 7)) * 16;
    }
    #pragma unroll
    for (int ni = 0; ni < 4; ++ni) {
        const int rt = wn * 64 + ni * 16 + lr;
        boff[ni] = rt * 64 + (lq ^ (rt & 3)) * 16;
    }

    f32x4 acc[4][4];
    #pragma unroll
    for (int mi = 0; mi < 4; ++mi)
        #pragma unroll
        for (int ni = 0; ni < 4; ++ni)
            acc[mi][ni] = (f32x4){0.f, 0.f, 0.f, 0.f};

#define COMPUTE(abuf, bbuf) do {                                            \
    short8 af[4], bfr[4];                                                   \
    _Pragma("unroll")                                                       \
    for (int mi = 0; mi < 4; ++mi) {                                        \
        const float4 lo = *(const float4*)&Ab[abuf][aoff0[mi]];             \
        const float4 hi = *(const float4*)&Ab[abuf][aoff1[mi]];             \
        short8 a8;                                                          \
        a8[0] = cvt1(lo.x); a8[1] = cvt1(lo.y);                             \
        a8[2] = cvt1(lo.z); a8[3] = cvt1(lo.w);                             \
        a8[4] = cvt1(hi.x); a8[5] = cvt1(hi.y);                             \
        a8[6] = cvt1(hi.z); a8[7] = cvt1(hi.w);                             \
        af[mi] = a8;                                                        \
    }                                                                       \
    _Pragma("unroll")                                                       \
    for (int ni = 0; ni < 4; ++ni)                                          \
        bfr[ni] = *(const short8*)&Bb[bbuf][boff[ni]];                      \
    _Pragma("unroll")                                                       \
    for (int mi = 0; mi < 4; ++mi)                                          \
        _Pragma("unroll")                                                   \
        for (int ni = 0; ni < 4; ++ni)                                      \
            acc[mi][ni] = __builtin_amdgcn_mfma_f32_16x16x32_bf16(          \
                af[mi], bfr[ni], acc[mi][ni], 0, 0, 0);                     \
} while (0)

#define VMW(n) do {                                                         \
    asm volatile("s_waitcnt vmcnt(" #n ")" ::: "memory");                   \
    __builtin_amdgcn_sched_barrier(0); } while (0)
#define SBAR do {                                                           \
    __builtin_amdgcn_sched_barrier(0);                                      \
    asm volatile("s_waitcnt lgkmcnt(0)" ::: "memory");                      \
    __builtin_amdgcn_s_barrier();                                           \
    __builtin_amdgcn_sched_barrier(0); } while (0)

    // ---- prologue: A(0)->0, B(0)->0, A(1)->1 ----
    STAGE_A(W(0), 0);
    STAGE_B(W(0), 0);
    STAGE_A(W(1), 1);

    int abf = 0;                   // t % 3 at loop top
    #pragma unroll 1
    for (int t = 0; t < NT - 1; ++t) {
        VMW(2);                    // retire A(t)+B(t); keep A(t+1) in flight
        SBAR;                      // compute(t-1) reads proven done
        STAGE_B(W(t + 1), (t + 1) & 1);
        if (t + 2 < NT) {
            int ab2 = abf + 2; if (ab2 >= 3) ab2 -= 3;
            STAGE_A(W(t + 2), ab2);
        }
        COMPUTE(abf, t & 1);
        ++abf; if (abf == 3) abf = 0;
    }
    // ---- last step t = NT-1 ----
    VMW(0);
    SBAR;
    COMPUTE(abf, (NT - 1) & 1);
    __syncthreads();

#undef W
#undef STAGE_A
#undef STAGE_B
#undef COMPUTE
#undef VMW
#undef SBAR

    // ---- fused trace epilogue ----
    // acc[mi][ni][j]: row = rb*128 + wm*64 + mi*16 + lq*4 + j, time = wn*64 + ni*16 + lr
    float* plds = (float*)&Ab[0][0];   // 2 x 256 floats (LDS free now)

    #pragma unroll
    for (int ni = 0; ni < 4; ++ni) {
        const int a_idx = wn * 64 + ni * 16 + lr;
        float ps = 0.f;
        #pragma unroll
        for (int mi = 0; mi < 4; ++mi) {
            const int bg = rb * 128 + wm * 64 + mi * 16 + lq * 4;
            const ushort4 w = *(const ushort4*)(obf + (size_t)a_idx * DDIM + bg);
            ps += bf2f(w.x) * acc[mi][ni][0];
            ps += bf2f(w.y) * acc[mi][ni][1];
            ps += bf2f(w.z) * acc[mi][ni][2];
            ps += bf2f(w.w) * acc[mi][ni][3];
        }
        ps += __shfl_xor(ps, 16);
        ps += __shfl_xor(ps, 32);
        if (lane < 16) plds[wm * 256 + a_idx] = ps;
    }
    __syncthreads();
    if (tid < 256)
        part[((size_t)d * 16 + rb) * TTIMES + tid] = plds[tid] + plds[256 + tid];
}

// ---------------- final reduce over row-blocks ----------------
__global__ void reduce_part(const float* __restrict__ part, float* __restrict__ out) {
    const int d = blockIdx.x;    // 32
    const int a = threadIdx.x;   // 256
    float s = 0.f;
    #pragma unroll
    for (int rb = 0; rb < 16; ++rb)
        s += part[((size_t)d * 16 + rb) * TTIMES + a];
    out[(size_t)d * TTIMES + a] = s;
}

extern "C" void kernel_launch(void* const* d_in, const int* in_sizes, int n_in,
                              void* d_out, int out_size, void* d_ws, size_t ws_size,
                              hipStream_t stream) {
    const float* x   = (const float*)d_in[0];   // (32, 2048, 2048) fp32
    const float* org = (const float*)d_in[1];   // (256, 2048) fp32
    float* out = (float*)d_out;                 // (32, 256) fp32

    ushort* obf = (ushort*)d_ws;                          // 1 MiB bf16 normalized o
    float*  prt = (float*)((char*)d_ws + (1 << 20));      // 512 KiB partials (32x16x256)

    norm_rows<<<dim3(TTIMES), dim3(256), 0, stream>>>(org, obf);
    gemm_trace<<<dim3(16, 32), dim3(THREADS), 0, stream>>>(x, obf, prt);
    reduce_part<<<dim3(32), dim3(256), 0, stream>>>(prt, out);
}